// Round 6
// baseline (5299.668 us; speedup 1.0000x reference)
//
#include <hip/hip_runtime.h>
#include <hip/hip_bf16.h>

using bf16 = __hip_bfloat16;
typedef __attribute__((ext_vector_type(8))) short short8;
typedef __attribute__((ext_vector_type(4))) float f32x4;

#define DEVI __device__ __forceinline__

#define MTOT 16384      // 64 * 16 * 16 output positions
#define PADS 25600      // 64 * 20 * 20 padded positions

DEVI float sigm_(float x){ return 1.f/(1.f+expf(-x)); }

// padded spatial index (row) for interior position m = ((nb*16)+iy)*16+ix
DEVI long pidx_(int m){
  int nb = m>>8, iy=(m>>4)&15, ix=m&15;
  return (long)(nb*20 + iy + 2)*20 + (ix + 2);
}

// async global->LDS, 16B per lane. LDS dest = wave-uniform base + lane*16.
DEVI void async16(const void* g, void* l) {
  __builtin_amdgcn_global_load_lds(
      (__attribute__((address_space(1))) void*)(unsigned long long)g,
      (__attribute__((address_space(3))) void*)(unsigned int)(unsigned long long)l,
      16, 0, 0);
}

// fused counted-vmcnt wait + barrier (for the small post kernel)
template<int N> DEVI void waitbar(){
  if constexpr (N==0)      asm volatile("s_waitcnt vmcnt(0)\ns_barrier" ::: "memory");
  else if constexpr (N==2) asm volatile("s_waitcnt vmcnt(2)\ns_barrier" ::: "memory");
  else                     asm volatile("s_waitcnt vmcnt(3)\ns_barrier" ::: "memory");
}

// ---------------------------------------------------------------------------
// Phase-pipelined implicit-GEMM conv. BM=128, BN=128, BK=32, 256 threads
// (4 waves 2Mx2N, wave tile 64x64 -> 8 ds_read_b128 : 16 MFMA per phase).
// Grid 512 blocks = 2 independent blocks/CU (inter-block overlap fills
// barrier slack). Triple-buffered LDS (48KB), depth-2 prefetch, counted
// vmcnt(4) confirmed ONE BARRIER BEFORE first read of each tile (cross-wave
// DMA visibility), setprio around MFMA cluster, XCD-chunked block swizzle.
// Source-side XOR swizzle (conflict-free ds_read, measured 0 in r2-r5).
// EPI: 1 = bf16 out stride 512 (+bias)                     [gates]
//      2 = s_enc: bf16 padded stride 416, +b(n<394) +ST +h_dec(n<128)
//      4 = fused decT+prior: n<352 -> sDec (+b(n<327)+ST); n>=384 -> PriorO f32
// ---------------------------------------------------------------------------
template<int CA, int EPI>
__global__ __launch_bounds__(256)
void conv_gemmP(const bf16* __restrict__ A, const bf16* __restrict__ Bt,
                const float* __restrict__ bias, const float* __restrict__ bias2,
                float* __restrict__ outF, bf16* __restrict__ outB,
                const bf16* __restrict__ ST, const bf16* __restrict__ extra)
{
  constexpr int Kp = 25*CA;
  constexpr int NS = Kp/32;            // BK=32 sub-tiles
  __shared__ alignas(16) bf16 As[3][128*32];
  __shared__ alignas(16) bf16 Bs[3][128*32];

  // XCD-chunked bijective swizzle (nwg = 512 = 8 XCD * 64)
  const int bid = blockIdx.y*gridDim.x + blockIdx.x;
  const int sid = ((bid & 7) << 6) + (bid >> 3);
  const int m0 = (sid & 127) << 7;
  const int n0 = (sid >> 7) << 7;

  const int tid = threadIdx.x;
  const int wv = tid>>6, ln = tid&63;

  // staging: A tile 128x32 = 512 chunks of 16B, B same; thread t handles
  // chunks t and t+256 of each. row = chunk>>2, phys chunk q = t&3 holds
  // logical chunk q ^ ((row>>1)&3) via pre-swizzled source address.
  const int rA = tid>>2;
  const int qs = ((tid&3) ^ ((rA>>1)&3))<<3;
  const int mA0 = m0 + rA, mA1 = m0 + rA + 64;
  const long paA0 = ((long)(((mA0>>8)*20 + ((mA0>>4)&15))*20 + (mA0&15)))*CA + qs;
  const long paA1 = ((long)(((mA1>>8)*20 + ((mA1>>4)&15))*20 + (mA1&15)))*CA + qs;
  const long pbB0 = (long)(n0 + rA)*Kp + qs;
  const long pbB1 = (long)(n0 + rA + 64)*Kp + qs;

  int kh=0, kw=0, c0=0, ks=0;
  auto stage = [&](int d){
    const long sh = (long)(kh*20 + kw)*CA + c0;
    char* la = (char*)(&As[d][0]) + (wv<<10);
    char* lb = (char*)(&Bs[d][0]) + (wv<<10);
    async16(A + paA0 + sh, la);
    async16(A + paA1 + sh, la + 4096);
    async16(Bt + pbB0 + ks, lb);
    async16(Bt + pbB1 + ks, lb + 4096);
    ks += 32;
    c0 += 32; if (c0==CA){ c0=0; if(++kw==5){kw=0; ++kh;} }
  };

  f32x4 acc[4][4] = {};
  const int wm = wv>>1, wn = wv&1;
  const int rowA = (wm<<6) + (ln&15);
  const int rowB = (wn<<6) + (ln&15);
  const int kqA = (((ln>>4) ^ ((rowA>>1)&3))<<4);   // invariant across +16k rows
  const int kqB = (((ln>>4) ^ ((rowB>>1)&3))<<4);

  stage(0); stage(1);
  asm volatile("s_waitcnt vmcnt(4)" ::: "memory");   // tile 0 landed
  asm volatile("s_barrier" ::: "memory");            // ...for all waves

  int bc = 0, bs = 2;
  for (int p=0; p<NS; ++p) {
    // phase p: read frags of tile p (confirmed at previous barrier),
    // issue stage(p+2), confirm stage(p+1), barrier, MFMA, barrier.
    const char* as_ = (const char*)(&As[bc][0]);
    const char* bs_ = (const char*)(&Bs[bc][0]);
    short8 af[4], bfr[4];
    #pragma unroll
    for (int mf=0; mf<4; mf++)
      af[mf] = *(const short8*)(as_ + ((rowA + (mf<<4))<<6) + kqA);
    #pragma unroll
    for (int nf=0; nf<4; nf++)
      bfr[nf] = *(const short8*)(bs_ + ((rowB + (nf<<4))<<6) + kqB);

    if (p+2 < NS) {
      stage(bs);
      asm volatile("s_waitcnt vmcnt(4)" ::: "memory");  // tile p+1 landed
    } else {
      asm volatile("s_waitcnt vmcnt(0)" ::: "memory");
    }
    asm volatile("s_barrier" ::: "memory");             // tile p+1 globally ready

    __builtin_amdgcn_s_setprio(1);
    #pragma unroll
    for (int mf=0; mf<4; mf++)
      #pragma unroll
      for (int nf=0; nf<4; nf++)
        acc[mf][nf] = __builtin_amdgcn_mfma_f32_16x16x32_bf16(af[mf], bfr[nf], acc[mf][nf], 0,0,0);
    __builtin_amdgcn_s_setprio(0);
    asm volatile("s_barrier" ::: "memory");             // close phase
    bc = (bc==2)?0:bc+1; bs = (bs==2)?0:bs+1;
  }

  const int mb = m0 + (wm<<6);
  const int nb = n0 + (wn<<6);
  const int ml = (ln>>4)<<2;
  const int nl = ln&15;
  #pragma unroll
  for (int mf=0; mf<4; mf++) {
    #pragma unroll
    for (int j=0; j<4; j++) {
      const int m = mb + (mf<<4) + ml + j;
      const long pI = pidx_(m);
      #pragma unroll
      for (int nf=0; nf<4; nf++) {
        const int n = nb + (nf<<4) + nl;
        const float v = acc[mf][nf][j];
        if constexpr (EPI==1) {
          outB[((long)m<<9) + n] = __float2bfloat16(v + bias[n]);
        } else if constexpr (EPI==2) {
          if (n < 416) {
            float b  = (n < 394) ? bias[n] : 0.f;
            float st = __bfloat162float(ST[(long)m*416 + n]);
            float e  = (n < 128) ? __bfloat162float(extra[(pI<<7) + n]) : 0.f;
            outB[pI*416 + n] = __float2bfloat16(v + b + st + e);
          }
        } else { // EPI==4
          if (n < 352) {
            float b  = (n < 327) ? bias[n] : 0.f;
            float st = __bfloat162float(ST[(long)m*352 + n]);
            outB[pI*352 + n] = __float2bfloat16(v + b + st);
          } else if (n >= 384) {
            outF[((long)m<<7) + (n-384)] = v + bias2[n-384];
          }
        }
      }
    }
  }
}

// ---------------------------------------------------------------------------
// small 4-wave GEMM (kept for post: M=16384, N=128, K=3200). TM=TN=64.
// ---------------------------------------------------------------------------
template<int TM, int TN, int CA, int EPI>
__global__ __launch_bounds__(256)
void conv_gemm(const bf16* __restrict__ A, const bf16* __restrict__ Bt,
               const float* __restrict__ bias, const float* __restrict__ bias2,
               float* __restrict__ outF, bf16* __restrict__ outB,
               const bf16* __restrict__ ST, const bf16* __restrict__ extra)
{
  constexpr int Kp  = 25*CA;
  constexpr int NK  = Kp/32;
  constexpr int MW  = (TM==128 && TN==64) ? 4 : 2;   // waves along M
  constexpr int NW  = 4/MW;
  constexpr int MFR = TM/(MW*16);
  constexpr int NFR = TN/(NW*16);
  constexpr int LPI = (TM==128 ? 2 : 1) + 1;         // per-wave loads/iter

  __shared__ alignas(16) bf16 As[2][TM*32];
  __shared__ alignas(16) bf16 Bs[2][TN*32];

  const int tid = threadIdx.x;
  const int wv = tid>>6, ln = tid&63;
  const int m0 = blockIdx.x*TM;
  const int n0 = blockIdx.y*TN;

  const int rA = tid>>2;
  const int qs = (tid&3) ^ ((tid>>3)&3);
  const int mA0 = m0 + rA, mA1 = m0 + rA + 64;
  const long paA0 = ((long)(((mA0>>8)*20 + ((mA0>>4)&15))*20 + (mA0&15)))*CA + qs*8;
  const long paA1 = ((long)(((mA1>>8)*20 + ((mA1>>4)&15))*20 + (mA1&15)))*CA + qs*8;
  const long pbB  = (long)(n0 + rA)*Kp + qs*8;

  auto stage = [&](int d, long sh, int k0){
    char* la = (char*)(&As[d][0]) + (wv<<10);
    char* lb = (char*)(&Bs[d][0]) + (wv<<10);
    async16(A + paA0 + sh, la);
    if constexpr (TM==128) async16(A + paA1 + sh, la + 4096);
    async16(Bt + pbB + k0, lb);
  };

  f32x4 acc[MFR][NFR] = {};

  const int wm = wv / NW, wn = wv % NW;
  const int rowA = wm*(TM/MW) + (ln&15);
  const int rowB = wn*(TN/NW) + (ln&15);
  const int kqA = (((ln>>4) ^ ((rowA>>1)&3))<<4);
  const int kqB = (((ln>>4) ^ ((rowB>>1)&3))<<4);

  int kh=0, kw=0, c0=0;
  auto adv = [&](){ c0 += 32; if (c0==CA){ c0=0; if(++kw==5){kw=0; ++kh;} } };

  stage(0, 0, 0); adv();
  int cur = 0;
  for (int step=0; step<NK; ++step) {
    if (step+1 < NK) {
      stage(cur^1, (long)(kh*20 + kw)*CA + c0, (step+1)*32);
      adv();
      waitbar<LPI>();
    } else {
      waitbar<0>();
    }

    short8 af[MFR], bfr[NFR];
    #pragma unroll
    for (int mf=0; mf<MFR; mf++)
      af[mf] = *(const short8*)((const char*)(&As[cur][0]) + ((rowA + (mf<<4))<<6) + kqA);
    #pragma unroll
    for (int nf=0; nf<NFR; nf++)
      bfr[nf] = *(const short8*)((const char*)(&Bs[cur][0]) + ((rowB + (nf<<4))<<6) + kqB);
    #pragma unroll
    for (int mf=0; mf<MFR; mf++)
      #pragma unroll
      for (int nf=0; nf<NFR; nf++)
        acc[mf][nf] = __builtin_amdgcn_mfma_f32_16x16x32_bf16(af[mf], bfr[nf], acc[mf][nf], 0,0,0);

    asm volatile("s_barrier" ::: "memory");
    cur ^= 1;
  }

  const int mb = m0 + wm*(TM/MW);
  const int nb = n0 + wn*(TN/NW);
  const int ml = (ln>>4)<<2;
  const int nl = ln&15;
  #pragma unroll
  for (int mf=0; mf<MFR; mf++) {
    #pragma unroll
    for (int j=0; j<4; j++) {
      const int m = mb + (mf<<4) + ml + j;
      #pragma unroll
      for (int nf=0; nf<NFR; nf++) {
        const int n = nb + (nf<<4) + nl;
        const float v = acc[mf][nf][j];
        if constexpr (EPI==0) {
          outF[((long)m<<7) + n] = v + bias[n];
        }
      }
    }
  }
}

// OIHW f32 -> Bt[n=o][k=(kh*5+kw)*CA + c] bf16, rows o>=O and cols c>=I zeroed.
__global__ void repack_w_k(const float* __restrict__ w, bf16* __restrict__ Bt,
                           int O, int I, int CA, long total)
{
  long e = (long)blockIdx.x*256 + threadIdx.x;
  if (e >= total) return;
  const int Kp = 25*CA;
  int o = (int)(e / Kp);
  int k = (int)(e % Kp);
  int blk = k / CA, c = k % CA;
  int kh = blk / 5, kwi = blk % 5;
  float v = 0.f;
  if (o < O && c < I) v = w[((long)o*I + c)*25 + kh*5 + kwi];
  Bt[e] = __float2bfloat16(v);
}

// Wcomb[c][pix*3+o] = sum_m write_w[c,m,ki,kj] * obs_w[o,m]   (pix = ki*4+kj)
__global__ void wcomb_k(const float* __restrict__ ww, const float* __restrict__ ow,
                        float* __restrict__ Wc)
{
  int idx = blockIdx.x*256 + threadIdx.x;
  if (idx >= 128*48) return;
  int c = idx / 48, rst = idx % 48;
  int pix = rst / 3, o = rst % 3;
  int ki = pix >> 2, kj = pix & 3;
  float a = 0.f;
  for (int mm=0; mm<128; mm++)
    a += ww[(((long)c*128 + mm)*4 + ki)*4 + kj] * ow[o*128 + mm];
  Wc[idx] = a;
}

// xr = conv(x, read_w, stride 4), xr[m*3+o]
__global__ void xr_k(const float* __restrict__ x, const float* __restrict__ rw,
                     float* __restrict__ xr)
{
  int idx = blockIdx.x*256 + threadIdx.x;
  if (idx >= MTOT*3) return;
  int m = idx / 3, o = idx % 3;
  int nb = m>>8, iy=(m>>4)&15, ix=m&15;
  float a = 0.f;
  for (int c=0;c<3;c++)
    for (int kh=0;kh<4;kh++)
      for (int kw=0;kw<4;kw++)
        a += x[((long)(nb*3+c)*64 + (iy*4+kh))*64 + (ix*4+kw)] * rw[((o*3+c)*4+kh)*4+kw];
  xr[idx] = a;
}

// static concat part for enc: channels 128..393 of ST_enc (stride 416)
__global__ void st_enc_k(const float* __restrict__ xr, const float* __restrict__ v,
                         const float* __restrict__ r, bf16* __restrict__ ST)
{
  long g = (long)blockIdx.x*256 + threadIdx.x;
  if (g >= (long)MTOT*266) return;
  int m = (int)(g / 266), ch = (int)(g % 266);
  int nb = m>>8, sp = m&255;
  float val;
  if (ch < 3)       val = xr[m*3 + ch];
  else if (ch < 10) val = v[nb*7 + ch - 3];
  else              val = r[((long)nb*256 + (ch-10))*256 + sp];
  ST[(long)m*416 + 128 + ch] = __float2bfloat16(val);
}

// static concat part for dec: channels 64..326 of ST_dec (stride 352)
__global__ void st_dec_k(const float* __restrict__ v, const float* __restrict__ r,
                         bf16* __restrict__ ST)
{
  long g = (long)blockIdx.x*256 + threadIdx.x;
  if (g >= (long)MTOT*263) return;
  int m = (int)(g / 263), ch = (int)(g % 263);
  int nb = m>>8, sp = m&255;
  float val;
  if (ch < 7) val = v[nb*7 + ch];
  else        val = r[((long)nb*256 + (ch-7))*256 + sp];
  ST[(long)m*352 + 64 + ch] = __float2bfloat16(val);
}

// LSTM pointwise: gates (f,i,o,s order, stride 512) -> c (f32), h (bf16 padded)
__global__ void lstm_k(const bf16* __restrict__ gates, float* __restrict__ cbuf,
                       bf16* __restrict__ hpad)
{
  int idx = blockIdx.x*256 + threadIdx.x;   // exactly MTOT*128
  int m = idx >> 7, c = idx & 127;
  long gb = (long)m << 9;
  float f = __bfloat162float(gates[gb + c]);
  float i = __bfloat162float(gates[gb + 128 + c]);
  float o = __bfloat162float(gates[gb + 256 + c]);
  float s = __bfloat162float(gates[gb + 384 + c]);
  float cell = sigm_(f)*cbuf[idx] + sigm_(i)*tanhf(s);
  cbuf[idx] = cell;
  hpad[(pidx_(m)<<7) + c] = __float2bfloat16(sigm_(o)*tanhf(cell));
}

// z = q_mu + exp(0.5 q_lv)*eps ; ADD z into sDec ch 0..63 ; KL partial per block
__global__ void zkl_k(const float* __restrict__ post, const float* __restrict__ prior,
                      const float* __restrict__ eps_t, bf16* __restrict__ sDec,
                      float* __restrict__ part)
{
  __shared__ float wsum[4];
  int idx = blockIdx.x*256 + threadIdx.x;   // exactly MTOT*64
  int m = idx >> 6, c = idx & 63;
  long pb = (long)m << 7;
  float qm = post[pb + c],  ql = post[pb + 64 + c];
  float pm = prior[pb + c], pl = prior[pb + 64 + c];
  int nb = m>>8, sp = m&255;
  float e = eps_t[((long)nb*64 + c)*256 + sp];
  float z = qm + expf(0.5f*ql)*e;
  long so = pidx_(m)*352 + c;
  sDec[so] = __float2bfloat16(__bfloat162float(sDec[so]) + z);
  float kl = expf(ql - pl) + (pm-qm)*(pm-qm)*expf(-pl) - 1.f + (pl - ql);
  #pragma unroll
  for (int off=32; off>0; off>>=1) kl += __shfl_down(kl, off);
  if ((threadIdx.x & 63) == 0) wsum[threadIdx.x >> 6] = kl;
  __syncthreads();
  if (threadIdx.x == 0)
    part[blockIdx.x] = wsum[0] + wsum[1] + wsum[2] + wsum[3];
}

// canvas pre-activation accumulate: uc[n,y,x,o] += sum_c h_dec*Wcomb
__global__ __launch_bounds__(256)
void wrc_k(const bf16* __restrict__ hpad, const float* __restrict__ Wc,
           float* __restrict__ uc)
{
  __shared__ float Wl[128*48];
  for (int i = threadIdx.x; i < 128*48; i += 256) Wl[i] = Wc[i];
  __syncthreads();
  int t = threadIdx.x;
  int mloc = t >> 4, pix = t & 15;
  int m = (blockIdx.x<<4) + mloc;
  int nb = m>>8, iy=(m>>4)&15, ix=m&15;
  const bf16* h = hpad + (pidx_(m)<<7);
  float a0=0.f, a1=0.f, a2=0.f;
  for (int c=0;c<128;c++) {
    float hv = __bfloat162float(h[c]);
    const float* wl = Wl + c*48 + pix*3;
    a0 += hv*wl[0]; a1 += hv*wl[1]; a2 += hv*wl[2];
  }
  int ki = pix>>2, kj = pix&3;
  long ob = ((long)((nb<<6) + (iy<<2) + ki)*64 + (ix<<2) + kj)*3;
  uc[ob+0] += a0; uc[ob+1] += a1; uc[ob+2] += a2;
}

__global__ void canvas_k(const float* __restrict__ uc, const float* __restrict__ ob,
                         float* __restrict__ out)
{
  int idx = blockIdx.x*256 + threadIdx.x;   // exactly 786432, NCHW order
  int x = idx & 63, y = (idx>>6)&63;
  int rem = idx >> 12;
  int o = rem % 3, n = rem / 3;
  float v = uc[((long)((n<<6)+y)*64 + x)*3 + o] + ob[o];
  out[idx] = 1.f/(1.f+expf(-v));
}

// final KL: sum 8*4096 per-block partials, scale, write out[786432]
__global__ void klred_k(const float* __restrict__ part, float* __restrict__ out)
{
  __shared__ float wsum[4];
  float a = 0.f;
  for (int i = threadIdx.x; i < 32768; i += 256) a += part[i];
  #pragma unroll
  for (int off=32; off>0; off>>=1) a += __shfl_down(a, off);
  if ((threadIdx.x & 63) == 0) wsum[threadIdx.x >> 6] = a;
  __syncthreads();
  if (threadIdx.x == 0)
    out[786432] = (wsum[0] + wsum[1] + wsum[2] + wsum[3]) * (0.5f/64.f);
}

// ---------------------------------------------------------------------------
// workspace layout (bytes)
static const long O_BT_POST  = 0;                     // 128*3200*2
static const long O_BT_ENCT  = O_BT_POST  + 819200;   // 512*3200*2
static const long O_BT_DP    = O_BT_ENCT  + 3276800;  // 512*3200*2 (decT rows 0..383, prior rows 384..511)
static const long O_BT_ENCG  = O_BT_DP    + 3276800;  // 512*10400*2
static const long O_BT_DECG  = O_BT_ENCG  + 10649600; // 512*8800*2
static const long O_WCOMB    = O_BT_DECG  + 9011200;  // 6144*4
static const long O_XR       = O_WCOMB    + 24576;    // 49152*4
static const long O_KLP      = O_XR       + 196608;   // 32768*4 per-block KL partials
static const long O_STENC    = O_KLP      + 131072;   // 16384*416*2
static const long O_STDEC    = O_STENC    + 13631488; // 16384*352*2
static const long O_HENC     = O_STDEC    + 11534336; // 25600*128*2
static const long O_HDEC     = O_HENC     + 6553600;
static const long O_SENC     = O_HDEC     + 6553600;  // 25600*416*2
static const long O_SDEC     = O_SENC     + 21299200; // 25600*352*2
static const long O_CENC     = O_SDEC     + 18022400; // 16384*128*4
static const long O_CDEC     = O_CENC     + 8388608;
static const long O_PRIOR    = O_CDEC     + 8388608;  // 16384*128*4
static const long O_POST     = O_PRIOR    + 8388608;
static const long O_GATES    = O_POST     + 8388608;  // 16384*512*2
static const long O_UC       = O_GATES    + 16777216; // 786432*4
static const long WS_TOTAL   = O_UC       + 3145728;

extern "C" void kernel_launch(void* const* d_in, const int* in_sizes, int n_in,
                              void* d_out, int out_size, void* d_ws, size_t ws_size,
                              hipStream_t stream)
{
  const float* x       = (const float*)d_in[0];
  const float* v       = (const float*)d_in[1];
  const float* r       = (const float*)d_in[2];
  const float* eps     = (const float*)d_in[3];
  const float* read_w  = (const float*)d_in[4];
  const float* write_w = (const float*)d_in[5];
  const float* prior_w = (const float*)d_in[6];
  const float* prior_b = (const float*)d_in[7];
  const float* post_w  = (const float*)d_in[8];
  const float* post_b  = (const float*)d_in[9];
  const float* enc_gw  = (const float*)d_in[10];
  const float* enc_gb  = (const float*)d_in[11];
  const float* enc_tw  = (const float*)d_in[12];
  const float* enc_tb  = (const float*)d_in[13];
  const float* dec_gw  = (const float*)d_in[14];
  const float* dec_gb  = (const float*)d_in[15];
  const float* dec_tw  = (const float*)d_in[16];
  const float* dec_tb  = (const float*)d_in[17];
  const float* obs_w   = (const float*)d_in[18];
  const float* obs_b   = (const float*)d_in[19];

  char* ws = (char*)d_ws;
  bf16* BtPost  = (bf16*)(ws + O_BT_POST);
  bf16* BtEncT  = (bf16*)(ws + O_BT_ENCT);
  bf16* BtDP    = (bf16*)(ws + O_BT_DP);
  bf16* BtEncG  = (bf16*)(ws + O_BT_ENCG);
  bf16* BtDecG  = (bf16*)(ws + O_BT_DECG);
  float* Wcomb  = (float*)(ws + O_WCOMB);
  float* XR     = (float*)(ws + O_XR);
  float* KLpart = (float*)(ws + O_KLP);
  bf16* STenc   = (bf16*)(ws + O_STENC);
  bf16* STdec   = (bf16*)(ws + O_STDEC);
  bf16* hEnc    = (bf16*)(ws + O_HENC);
  bf16* hDec    = (bf16*)(ws + O_HDEC);
  bf16* sEnc    = (bf16*)(ws + O_SENC);
  bf16* sDec    = (bf16*)(ws + O_SDEC);
  float* cEnc   = (float*)(ws + O_CENC);
  float* cDec   = (float*)(ws + O_CDEC);
  float* PriorO = (float*)(ws + O_PRIOR);
  float* PostO  = (float*)(ws + O_POST);
  bf16* Gates   = (bf16*)(ws + O_GATES);
  float* Ucomb  = (float*)(ws + O_UC);
  float* out    = (float*)d_out;

  size_t clr = (size_t)WS_TOTAL; if (clr > ws_size) clr = ws_size;
  hipMemsetAsync(d_ws, 0, clr, stream);

  // weight repacks
  repack_w_k<<<1600, 256, 0, stream>>>(post_w,  BtPost, 128, 128, 128, 128L*3200);
  repack_w_k<<<6400, 256, 0, stream>>>(enc_tw,  BtEncT, 394, 128, 128, 512L*3200);
  repack_w_k<<<4800, 256, 0, stream>>>(dec_tw,  BtDP,   327, 128, 128, 384L*3200);
  repack_w_k<<<1600, 256, 0, stream>>>(prior_w, BtDP + 384L*3200, 128, 128, 128, 128L*3200);
  repack_w_k<<<20800,256, 0, stream>>>(enc_gw,  BtEncG, 512, 394, 416, 512L*10400);
  repack_w_k<<<17600,256, 0, stream>>>(dec_gw,  BtDecG, 512, 327, 352, 512L*8800);
  wcomb_k<<<24, 256, 0, stream>>>(write_w, obs_w, Wcomb);
  xr_k<<<192, 256, 0, stream>>>(x, read_w, XR);
  st_enc_k<<<(int)(((long)MTOT*266 + 255)/256), 256, 0, stream>>>(XR, v, r, STenc);
  st_dec_k<<<(int)(((long)MTOT*263 + 255)/256), 256, 0, stream>>>(v, r, STdec);

  for (int t = 0; t < 8; ++t) {
    // fused: sDec = decT(h_dec)+tb+ST (no z yet) ; PriorO = prior(h_dec)+pb
    conv_gemmP<128,4><<<dim3(128,4), 256, 0, stream>>>(
        hDec, BtDP, dec_tb, prior_b, PriorO, sDec, STdec, nullptr);
    // s_enc = encT(h_enc)+tb + [h_dec, xr, v, r]
    conv_gemmP<128,2><<<dim3(128,4), 256, 0, stream>>>(
        hEnc, BtEncT, enc_tb, nullptr, nullptr, sEnc, STenc, hDec);
    // enc gates
    conv_gemmP<416,1><<<dim3(128,4), 256, 0, stream>>>(
        sEnc, BtEncG, enc_gb, nullptr, nullptr, Gates, nullptr, nullptr);
    lstm_k<<<8192, 256, 0, stream>>>(Gates, cEnc, hEnc);
    // post = conv(h_enc) -> f32
    conv_gemm<64,64,128,0><<<dim3(256,2), 256, 0, stream>>>(
        hEnc, BtPost, post_b, nullptr, PostO, nullptr, nullptr, nullptr);
    // z -> add into sDec ch0..63 ; KL partials (no contended atomics)
    zkl_k<<<4096, 256, 0, stream>>>(PostO, PriorO, eps + (long)t*64*64*256,
                                    sDec, KLpart + (long)t*4096);
    // dec gates
    conv_gemmP<352,1><<<dim3(128,4), 256, 0, stream>>>(
        sDec, BtDecG, dec_gb, nullptr, nullptr, Gates, nullptr, nullptr);
    lstm_k<<<8192, 256, 0, stream>>>(Gates, cDec, hDec);
    // canvas accumulate (write conv fused with obs 1x1)
    wrc_k<<<1024, 256, 0, stream>>>(hDec, Wcomb, Ucomb);
  }

  canvas_k<<<3072, 256, 0, stream>>>(Ucomb, obs_b, out);
  klred_k<<<1, 256, 0, stream>>>(KLpart, out);
}

// Round 7
// 4007.159 us; speedup vs baseline: 1.3225x; 1.3225x over previous
//
#include <hip/hip_runtime.h>
#include <hip/hip_bf16.h>

using bf16 = __hip_bfloat16;
typedef __attribute__((ext_vector_type(8))) short short8;
typedef __attribute__((ext_vector_type(4))) float f32x4;

#define DEVI __device__ __forceinline__

#define MTOT 16384      // 64 * 16 * 16 output positions
#define PADS 25600      // 64 * 20 * 20 padded positions

DEVI float sigm_(float x){ return 1.f/(1.f+expf(-x)); }

// padded spatial index (row) for interior position m = ((nb*16)+iy)*16+ix
DEVI long pidx_(int m){
  int nb = m>>8, iy=(m>>4)&15, ix=m&15;
  return (long)(nb*20 + iy + 2)*20 + (ix + 2);
}

// async global->LDS, 16B per lane. LDS dest = wave-uniform base + lane*16.
DEVI void async16(const void* g, void* l) {
  __builtin_amdgcn_global_load_lds(
      (__attribute__((address_space(1))) void*)(unsigned long long)g,
      (__attribute__((address_space(3))) void*)(unsigned int)(unsigned long long)l,
      16, 0, 0);
}

// fused counted-vmcnt wait + barrier (single asm so no loads slip between)
template<int N> DEVI void waitbar(){
  if constexpr (N==0)      asm volatile("s_waitcnt vmcnt(0)\ns_barrier" ::: "memory");
  else if constexpr (N==2) asm volatile("s_waitcnt vmcnt(2)\ns_barrier" ::: "memory");
  else                     asm volatile("s_waitcnt vmcnt(3)\ns_barrier" ::: "memory");
}

// ---------------------------------------------------------------------------
// 8-wave implicit-GEMM conv body (round-4 champion schedule). BM=256, BN=128,
// BK=32, triple-buffered LDS, depth-2 prefetch, counted vmcnt(3), setprio.
// Natural m-major block order (bid%8 = x%8 clusters the 4 n-copies of each
// m-tile on one XCD -> tap re-reads hit L2; do NOT XCD-swizzle this shape).
// Sub-tile range [s0,s1) enables split-K. LDS passed in (shared across merged
// kernel variants).
// EPI: 1 = bf16 out stride 512 (+bias)                     [gates]
//      2 = s_enc: bf16 padded stride 416, +b(n<394) +ST +h_dec(n<128)
//      4 = fused decT+prior: n<352 -> sDec (+b(n<327)+ST); n>=384 -> PriorO f32
//      5 = bf16 PARTIAL out stride 512, no bias            [split-K gates]
// ---------------------------------------------------------------------------
template<int CA, int EPI>
DEVI void conv_body(const bf16* __restrict__ A, const bf16* __restrict__ Bt,
                    const float* __restrict__ bias, const float* __restrict__ bias2,
                    float* __restrict__ outF, bf16* __restrict__ outB,
                    const bf16* __restrict__ ST, const bf16* __restrict__ extra,
                    int s0, int s1, int m0, int n0,
                    bf16* AsBase, bf16* BsBase)
{
  constexpr int Kp = 25*CA;
  const int NS = s1 - s0;

  const int tid = threadIdx.x;
  const int wv = tid>>6, ln = tid&63;

  // staging: A tile 256x32 = 1024 chunks of 16B; B tile 128x32 = 512 chunks.
  // row = chunk>>2; phys chunk q holds logical q ^ ((row>>1)&3) (pre-swizzled
  // global source; ds_read conflict-free, measured 0 in r2-r5).
  const int rA = tid>>2;
  const int qs = ((tid&3) ^ ((rA>>1)&3))<<3;
  const int mA0 = m0 + rA, mA1 = m0 + 128 + rA;
  const long paA0 = ((long)(((mA0>>8)*20 + ((mA0>>4)&15))*20 + (mA0&15)))*CA + qs;
  const long paA1 = ((long)(((mA1>>8)*20 + ((mA1>>4)&15))*20 + (mA1&15)))*CA + qs;
  const long pbB  = (long)(n0 + rA)*Kp + qs;

  // K-cursor init from s0
  int kk0 = s0*32;
  int c0 = kk0 % CA;
  int tap = kk0 / CA;
  int kh = tap/5, kw = tap%5;
  int ks = kk0;

  auto stage = [&](int d){
    const long sh = (long)(kh*20 + kw)*CA + c0;
    char* la = (char*)AsBase + d*16384 + (wv<<10);
    char* lb = (char*)BsBase + d*8192  + (wv<<10);
    async16(A + paA0 + sh, la);
    async16(A + paA1 + sh, la + 8192);
    async16(Bt + pbB + ks, lb);
    ks += 32;
    c0 += 32; if (c0==CA){ c0=0; if(++kw==5){kw=0; ++kh;} }
  };

  f32x4 acc[4][4] = {};
  const int wm = wv>>1, wn = wv&1;
  const int rowA = (wm<<6) + (ln&15);
  const int rowB = (wn<<6) + (ln&15);
  const int kqA = (((ln>>4) ^ ((rowA>>1)&3))<<4);   // invariant across +16k rows
  const int kqB = (((ln>>4) ^ ((rowB>>1)&3))<<4);

  stage(0); stage(1);
  int bc = 0, bs = 2;
  for (int t=0; t<NS; ++t) {
    if (t+1 < NS) waitbar<3>();   // tile t's 3 loads (older than t+1's) done
    else          waitbar<0>();
    if (t+2 < NS) stage(bs);      // issue next-next tile (depth 2)

    const char* as_ = (const char*)AsBase + bc*16384;
    const char* bs_ = (const char*)BsBase + bc*8192;
    short8 af[4], bfr[4];
    #pragma unroll
    for (int mf=0; mf<4; mf++)
      af[mf] = *(const short8*)(as_ + ((rowA + (mf<<4))<<6) + kqA);
    #pragma unroll
    for (int nf=0; nf<4; nf++)
      bfr[nf] = *(const short8*)(bs_ + ((rowB + (nf<<4))<<6) + kqB);
    __builtin_amdgcn_s_setprio(1);
    #pragma unroll
    for (int mf=0; mf<4; mf++)
      #pragma unroll
      for (int nf=0; nf<4; nf++)
        acc[mf][nf] = __builtin_amdgcn_mfma_f32_16x16x32_bf16(af[mf], bfr[nf], acc[mf][nf], 0,0,0);
    __builtin_amdgcn_s_setprio(0);
    bc = (bc==2)?0:bc+1; bs = (bs==2)?0:bs+1;
  }

  const int mb = m0 + (wm<<6);
  const int nb = n0 + (wn<<6);
  const int ml = (ln>>4)<<2;
  const int nl = ln&15;
  #pragma unroll
  for (int mf=0; mf<4; mf++) {
    #pragma unroll
    for (int j=0; j<4; j++) {
      const int m = mb + (mf<<4) + ml + j;
      const long pI = pidx_(m);
      #pragma unroll
      for (int nf=0; nf<4; nf++) {
        const int n = nb + (nf<<4) + nl;
        const float v = acc[mf][nf][j];
        if constexpr (EPI==1) {
          outB[((long)m<<9) + n] = __float2bfloat16(v + bias[n]);
        } else if constexpr (EPI==2) {
          if (n < 416) {
            float b  = (n < 394) ? bias[n] : 0.f;
            float st = __bfloat162float(ST[(long)m*416 + n]);
            float e  = (n < 128) ? __bfloat162float(extra[(pI<<7) + n]) : 0.f;
            outB[pI*416 + n] = __float2bfloat16(v + b + st + e);
          }
        } else if constexpr (EPI==4) {
          if (n < 352) {
            float b  = (n < 327) ? bias[n] : 0.f;
            float st = __bfloat162float(ST[(long)m*352 + n]);
            outB[pI*352 + n] = __float2bfloat16(v + b + st);
          } else if (n >= 384) {
            outF[((long)m<<7) + (n-384)] = v + bias2[n-384];
          }
        } else { // EPI==5: split-K partial, no bias
          outB[((long)m<<9) + n] = __float2bfloat16(v);
        }
      }
    }
  }
}

// split-K gates GEMM: grid (64,4,2); z = K-half -> same (m,n) tile pairs
// co-resident per CU (independent work, shared A rows / B panel in L2).
template<int CA>
__global__ __launch_bounds__(512)
void conv_split(const bf16* __restrict__ A, const bf16* __restrict__ Bt,
                bf16* __restrict__ P0, bf16* __restrict__ P1)
{
  __shared__ alignas(16) bf16 As[3][256*32];
  __shared__ alignas(16) bf16 Bs[3][128*32];
  constexpr int NSUB = 25*CA/32;
  constexpr int H0 = NSUB - NSUB/2;
  const int z = blockIdx.z;
  conv_body<CA,5>(A, Bt, nullptr, nullptr, nullptr, z ? P1 : P0,
                  nullptr, nullptr, z ? H0 : 0, z ? NSUB : H0,
                  blockIdx.x<<8, blockIdx.y<<7, &As[0][0], &Bs[0][0]);
}

// merged decT+prior (z=0) and encT (z=1): independent convs, 2 blocks/CU.
__global__ __launch_bounds__(512)
void conv_tp(const bf16* __restrict__ hDec, const bf16* __restrict__ BtDP,
             const float* __restrict__ dec_tb, const float* __restrict__ prior_b,
             float* __restrict__ PriorO, bf16* __restrict__ sDec,
             const bf16* __restrict__ STdec,
             const bf16* __restrict__ hEnc, const bf16* __restrict__ BtEncT,
             const float* __restrict__ enc_tb, bf16* __restrict__ sEnc,
             const bf16* __restrict__ STenc)
{
  __shared__ alignas(16) bf16 As[3][256*32];
  __shared__ alignas(16) bf16 Bs[3][128*32];
  const int m0 = blockIdx.x<<8, n0 = blockIdx.y<<7;
  if (blockIdx.z == 0)
    conv_body<128,4>(hDec, BtDP, dec_tb, prior_b, PriorO, sDec, STdec, nullptr,
                     0, 100, m0, n0, &As[0][0], &Bs[0][0]);
  else
    conv_body<128,2>(hEnc, BtEncT, enc_tb, nullptr, nullptr, sEnc, STenc, hDec,
                     0, 100, m0, n0, &As[0][0], &Bs[0][0]);
}

// ---------------------------------------------------------------------------
// small 4-wave GEMM (post: M=16384, N=128, K=3200). TM=TN=64, EPI=0 f32 out.
// ---------------------------------------------------------------------------
template<int TM, int TN, int CA, int EPI>
__global__ __launch_bounds__(256)
void conv_gemm(const bf16* __restrict__ A, const bf16* __restrict__ Bt,
               const float* __restrict__ bias, float* __restrict__ outF)
{
  constexpr int Kp  = 25*CA;
  constexpr int NK  = Kp/32;
  constexpr int MW  = 2;
  constexpr int NW  = 2;
  constexpr int MFR = TM/(MW*16);
  constexpr int NFR = TN/(NW*16);

  __shared__ alignas(16) bf16 As[2][TM*32];
  __shared__ alignas(16) bf16 Bs[2][TN*32];

  const int tid = threadIdx.x;
  const int wv = tid>>6, ln = tid&63;
  const int m0 = blockIdx.x*TM;
  const int n0 = blockIdx.y*TN;

  const int rA = tid>>2;
  const int qs = (tid&3) ^ ((tid>>3)&3);
  const int mA0 = m0 + rA;
  const long paA0 = ((long)(((mA0>>8)*20 + ((mA0>>4)&15))*20 + (mA0&15)))*CA + qs*8;
  const long pbB  = (long)(n0 + rA)*Kp + qs*8;

  auto stage = [&](int d, long sh, int k0){
    char* la = (char*)(&As[d][0]) + (wv<<10);
    char* lb = (char*)(&Bs[d][0]) + (wv<<10);
    async16(A + paA0 + sh, la);
    async16(Bt + pbB + k0, lb);
  };

  f32x4 acc[MFR][NFR] = {};

  const int wm = wv / NW, wn = wv % NW;
  const int rowA = wm*(TM/MW) + (ln&15);
  const int rowB = wn*(TN/NW) + (ln&15);
  const int kqA = (((ln>>4) ^ ((rowA>>1)&3))<<4);
  const int kqB = (((ln>>4) ^ ((rowB>>1)&3))<<4);

  int kh=0, kw=0, c0=0;
  auto adv = [&](){ c0 += 32; if (c0==CA){ c0=0; if(++kw==5){kw=0; ++kh;} } };

  stage(0, 0, 0); adv();
  int cur = 0;
  for (int step=0; step<NK; ++step) {
    if (step+1 < NK) {
      stage(cur^1, (long)(kh*20 + kw)*CA + c0, (step+1)*32);
      adv();
      waitbar<2>();
    } else {
      waitbar<0>();
    }

    short8 af[MFR], bfr[NFR];
    #pragma unroll
    for (int mf=0; mf<MFR; mf++)
      af[mf] = *(const short8*)((const char*)(&As[cur][0]) + ((rowA + (mf<<4))<<6) + kqA);
    #pragma unroll
    for (int nf=0; nf<NFR; nf++)
      bfr[nf] = *(const short8*)((const char*)(&Bs[cur][0]) + ((rowB + (nf<<4))<<6) + kqB);
    #pragma unroll
    for (int mf=0; mf<MFR; mf++)
      #pragma unroll
      for (int nf=0; nf<NFR; nf++)
        acc[mf][nf] = __builtin_amdgcn_mfma_f32_16x16x32_bf16(af[mf], bfr[nf], acc[mf][nf], 0,0,0);

    asm volatile("s_barrier" ::: "memory");
    cur ^= 1;
  }

  const int mb = m0 + wm*(TM/MW);
  const int nb = n0 + wn*(TN/NW);
  const int ml = (ln>>4)<<2;
  const int nl = ln&15;
  #pragma unroll
  for (int mf=0; mf<MFR; mf++) {
    #pragma unroll
    for (int j=0; j<4; j++) {
      const int m = mb + (mf<<4) + ml + j;
      #pragma unroll
      for (int nf=0; nf<NFR; nf++) {
        const int n = nb + (nf<<4) + nl;
        outF[((long)m<<7) + n] = acc[mf][nf][j] + bias[n];
      }
    }
  }
}

// OIHW f32 -> Bt[n=o][k=(kh*5+kw)*CA + c] bf16, rows o>=O and cols c>=I zeroed.
__global__ void repack_w_k(const float* __restrict__ w, bf16* __restrict__ Bt,
                           int O, int I, int CA, long total)
{
  long e = (long)blockIdx.x*256 + threadIdx.x;
  if (e >= total) return;
  const int Kp = 25*CA;
  int o = (int)(e / Kp);
  int k = (int)(e % Kp);
  int blk = k / CA, c = k % CA;
  int kh = blk / 5, kwi = blk % 5;
  float v = 0.f;
  if (o < O && c < I) v = w[((long)o*I + c)*25 + kh*5 + kwi];
  Bt[e] = __float2bfloat16(v);
}

// Wcomb[c][pix*3+o] = sum_m write_w[c,m,ki,kj] * obs_w[o,m]   (pix = ki*4+kj)
__global__ void wcomb_k(const float* __restrict__ ww, const float* __restrict__ ow,
                        float* __restrict__ Wc)
{
  int idx = blockIdx.x*256 + threadIdx.x;
  if (idx >= 128*48) return;
  int c = idx / 48, rst = idx % 48;
  int pix = rst / 3, o = rst % 3;
  int ki = pix >> 2, kj = pix & 3;
  float a = 0.f;
  for (int mm=0; mm<128; mm++)
    a += ww[(((long)c*128 + mm)*4 + ki)*4 + kj] * ow[o*128 + mm];
  Wc[idx] = a;
}

// xr = conv(x, read_w, stride 4), xr[m*3+o]
__global__ void xr_k(const float* __restrict__ x, const float* __restrict__ rw,
                     float* __restrict__ xr)
{
  int idx = blockIdx.x*256 + threadIdx.x;
  if (idx >= MTOT*3) return;
  int m = idx / 3, o = idx % 3;
  int nb = m>>8, iy=(m>>4)&15, ix=m&15;
  float a = 0.f;
  for (int c=0;c<3;c++)
    for (int kh=0;kh<4;kh++)
      for (int kw=0;kw<4;kw++)
        a += x[((long)(nb*3+c)*64 + (iy*4+kh))*64 + (ix*4+kw)] * rw[((o*3+c)*4+kh)*4+kw];
  xr[idx] = a;
}

// static concat part for enc: channels 128..393 of ST_enc (stride 416)
__global__ void st_enc_k(const float* __restrict__ xr, const float* __restrict__ v,
                         const float* __restrict__ r, bf16* __restrict__ ST)
{
  long g = (long)blockIdx.x*256 + threadIdx.x;
  if (g >= (long)MTOT*266) return;
  int m = (int)(g / 266), ch = (int)(g % 266);
  int nb = m>>8, sp = m&255;
  float val;
  if (ch < 3)       val = xr[m*3 + ch];
  else if (ch < 10) val = v[nb*7 + ch - 3];
  else              val = r[((long)nb*256 + (ch-10))*256 + sp];
  ST[(long)m*416 + 128 + ch] = __float2bfloat16(val);
}

// static concat part for dec: channels 64..326 of ST_dec (stride 352)
__global__ void st_dec_k(const float* __restrict__ v, const float* __restrict__ r,
                         bf16* __restrict__ ST)
{
  long g = (long)blockIdx.x*256 + threadIdx.x;
  if (g >= (long)MTOT*263) return;
  int m = (int)(g / 263), ch = (int)(g % 263);
  int nb = m>>8, sp = m&255;
  float val;
  if (ch < 7) val = v[nb*7 + ch];
  else        val = r[((long)nb*256 + (ch-7))*256 + sp];
  ST[(long)m*352 + 64 + ch] = __float2bfloat16(val);
}

// LSTM pointwise over split-K partials: gates = P0+P1+bias (f,i,o,s, stride 512)
__global__ void lstm2_k(const bf16* __restrict__ P0, const bf16* __restrict__ P1,
                        const float* __restrict__ gb_, float* __restrict__ cbuf,
                        bf16* __restrict__ hpad)
{
  int idx = blockIdx.x*256 + threadIdx.x;   // exactly MTOT*128
  int m = idx >> 7, c = idx & 127;
  long gb = (long)m << 9;
  float f = __bfloat162float(P0[gb + c])       + __bfloat162float(P1[gb + c])       + gb_[c];
  float i = __bfloat162float(P0[gb + 128 + c]) + __bfloat162float(P1[gb + 128 + c]) + gb_[128 + c];
  float o = __bfloat162float(P0[gb + 256 + c]) + __bfloat162float(P1[gb + 256 + c]) + gb_[256 + c];
  float s = __bfloat162float(P0[gb + 384 + c]) + __bfloat162float(P1[gb + 384 + c]) + gb_[384 + c];
  float cell = sigm_(f)*cbuf[idx] + sigm_(i)*tanhf(s);
  cbuf[idx] = cell;
  hpad[(pidx_(m)<<7) + c] = __float2bfloat16(sigm_(o)*tanhf(cell));
}

// z = q_mu + exp(0.5 q_lv)*eps ; ADD z into sDec ch 0..63 ; KL partial per block
__global__ void zkl_k(const float* __restrict__ post, const float* __restrict__ prior,
                      const float* __restrict__ eps_t, bf16* __restrict__ sDec,
                      float* __restrict__ part)
{
  __shared__ float wsum[4];
  int idx = blockIdx.x*256 + threadIdx.x;   // exactly MTOT*64
  int m = idx >> 6, c = idx & 63;
  long pb = (long)m << 7;
  float qm = post[pb + c],  ql = post[pb + 64 + c];
  float pm = prior[pb + c], pl = prior[pb + 64 + c];
  int nb = m>>8, sp = m&255;
  float e = eps_t[((long)nb*64 + c)*256 + sp];
  float z = qm + expf(0.5f*ql)*e;
  long so = pidx_(m)*352 + c;
  sDec[so] = __float2bfloat16(__bfloat162float(sDec[so]) + z);
  float kl = expf(ql - pl) + (pm-qm)*(pm-qm)*expf(-pl) - 1.f + (pl - ql);
  #pragma unroll
  for (int off=32; off>0; off>>=1) kl += __shfl_down(kl, off);
  if ((threadIdx.x & 63) == 0) wsum[threadIdx.x >> 6] = kl;
  __syncthreads();
  if (threadIdx.x == 0)
    part[blockIdx.x] = wsum[0] + wsum[1] + wsum[2] + wsum[3];
}

// canvas pre-activation accumulate: uc[n,y,x,o] += sum_c h_dec*Wcomb
__global__ __launch_bounds__(256)
void wrc_k(const bf16* __restrict__ hpad, const float* __restrict__ Wc,
           float* __restrict__ uc)
{
  __shared__ float Wl[128*48];
  for (int i = threadIdx.x; i < 128*48; i += 256) Wl[i] = Wc[i];
  __syncthreads();
  int t = threadIdx.x;
  int mloc = t >> 4, pix = t & 15;
  int m = (blockIdx.x<<4) + mloc;
  int nb = m>>8, iy=(m>>4)&15, ix=m&15;
  const bf16* h = hpad + (pidx_(m)<<7);
  float a0=0.f, a1=0.f, a2=0.f;
  for (int c=0;c<128;c++) {
    float hv = __bfloat162float(h[c]);
    const float* wl = Wl + c*48 + pix*3;
    a0 += hv*wl[0]; a1 += hv*wl[1]; a2 += hv*wl[2];
  }
  int ki = pix>>2, kj = pix&3;
  long ob = ((long)((nb<<6) + (iy<<2) + ki)*64 + (ix<<2) + kj)*3;
  uc[ob+0] += a0; uc[ob+1] += a1; uc[ob+2] += a2;
}

__global__ void canvas_k(const float* __restrict__ uc, const float* __restrict__ ob,
                         float* __restrict__ out)
{
  int idx = blockIdx.x*256 + threadIdx.x;   // exactly 786432, NCHW order
  int x = idx & 63, y = (idx>>6)&63;
  int rem = idx >> 12;
  int o = rem % 3, n = rem / 3;
  float v = uc[((long)((n<<6)+y)*64 + x)*3 + o] + ob[o];
  out[idx] = 1.f/(1.f+expf(-v));
}

// final KL: sum 8*4096 per-block partials, scale, write out[786432]
__global__ void klred_k(const float* __restrict__ part, float* __restrict__ out)
{
  __shared__ float wsum[4];
  float a = 0.f;
  for (int i = threadIdx.x; i < 32768; i += 256) a += part[i];
  #pragma unroll
  for (int off=32; off>0; off>>=1) a += __shfl_down(a, off);
  if ((threadIdx.x & 63) == 0) wsum[threadIdx.x >> 6] = a;
  __syncthreads();
  if (threadIdx.x == 0)
    out[786432] = (wsum[0] + wsum[1] + wsum[2] + wsum[3]) * (0.5f/64.f);
}

// ---------------------------------------------------------------------------
// workspace layout (bytes)
static const long O_BT_POST  = 0;                     // 128*3200*2
static const long O_BT_ENCT  = O_BT_POST  + 819200;   // 512*3200*2
static const long O_BT_DP    = O_BT_ENCT  + 3276800;  // 512*3200*2 (decT 0..383, prior 384..511)
static const long O_BT_ENCG  = O_BT_DP    + 3276800;  // 512*10400*2
static const long O_BT_DECG  = O_BT_ENCG  + 10649600; // 512*8800*2
static const long O_WCOMB    = O_BT_DECG  + 9011200;  // 6144*4
static const long O_XR       = O_WCOMB    + 24576;    // 49152*4
static const long O_KLP      = O_XR       + 196608;   // 32768*4 per-block KL partials
static const long O_STENC    = O_KLP      + 131072;   // 16384*416*2
static const long O_STDEC    = O_STENC    + 13631488; // 16384*352*2
static const long O_HENC     = O_STDEC    + 11534336; // 25600*128*2
static const long O_HDEC     = O_HENC     + 6553600;
static const long O_SENC     = O_HDEC     + 6553600;  // 25600*416*2
static const long O_SDEC     = O_SENC     + 21299200; // 25600*352*2
static const long O_CENC     = O_SDEC     + 18022400; // 16384*128*4
static const long O_CDEC     = O_CENC     + 8388608;
static const long O_PRIOR    = O_CDEC     + 8388608;  // 16384*128*4
static const long O_POST     = O_PRIOR    + 8388608;
static const long O_PG0      = O_POST     + 8388608;  // 16384*512*2 split-K partial 0
static const long O_PG1      = O_PG0      + 16777216; // 16384*512*2 split-K partial 1
static const long O_UC       = O_PG1      + 16777216; // 786432*4
static const long WS_TOTAL   = O_UC       + 3145728;  // ~175 MB

extern "C" void kernel_launch(void* const* d_in, const int* in_sizes, int n_in,
                              void* d_out, int out_size, void* d_ws, size_t ws_size,
                              hipStream_t stream)
{
  const float* x       = (const float*)d_in[0];
  const float* v       = (const float*)d_in[1];
  const float* r       = (const float*)d_in[2];
  const float* eps     = (const float*)d_in[3];
  const float* read_w  = (const float*)d_in[4];
  const float* write_w = (const float*)d_in[5];
  const float* prior_w = (const float*)d_in[6];
  const float* prior_b = (const float*)d_in[7];
  const float* post_w  = (const float*)d_in[8];
  const float* post_b  = (const float*)d_in[9];
  const float* enc_gw  = (const float*)d_in[10];
  const float* enc_gb  = (const float*)d_in[11];
  const float* enc_tw  = (const float*)d_in[12];
  const float* enc_tb  = (const float*)d_in[13];
  const float* dec_gw  = (const float*)d_in[14];
  const float* dec_gb  = (const float*)d_in[15];
  const float* dec_tw  = (const float*)d_in[16];
  const float* dec_tb  = (const float*)d_in[17];
  const float* obs_w   = (const float*)d_in[18];
  const float* obs_b   = (const float*)d_in[19];

  char* ws = (char*)d_ws;
  bf16* BtPost  = (bf16*)(ws + O_BT_POST);
  bf16* BtEncT  = (bf16*)(ws + O_BT_ENCT);
  bf16* BtDP    = (bf16*)(ws + O_BT_DP);
  bf16* BtEncG  = (bf16*)(ws + O_BT_ENCG);
  bf16* BtDecG  = (bf16*)(ws + O_BT_DECG);
  float* Wcomb  = (float*)(ws + O_WCOMB);
  float* XR     = (float*)(ws + O_XR);
  float* KLpart = (float*)(ws + O_KLP);
  bf16* STenc   = (bf16*)(ws + O_STENC);
  bf16* STdec   = (bf16*)(ws + O_STDEC);
  bf16* hEnc    = (bf16*)(ws + O_HENC);
  bf16* hDec    = (bf16*)(ws + O_HDEC);
  bf16* sEnc    = (bf16*)(ws + O_SENC);
  bf16* sDec    = (bf16*)(ws + O_SDEC);
  float* cEnc   = (float*)(ws + O_CENC);
  float* cDec   = (float*)(ws + O_CDEC);
  float* PriorO = (float*)(ws + O_PRIOR);
  float* PostO  = (float*)(ws + O_POST);
  bf16* PG0     = (bf16*)(ws + O_PG0);
  bf16* PG1     = (bf16*)(ws + O_PG1);
  float* Ucomb  = (float*)(ws + O_UC);
  float* out    = (float*)d_out;

  size_t clr = (size_t)WS_TOTAL; if (clr > ws_size) clr = ws_size;
  hipMemsetAsync(d_ws, 0, clr, stream);

  // weight repacks
  repack_w_k<<<1600, 256, 0, stream>>>(post_w,  BtPost, 128, 128, 128, 128L*3200);
  repack_w_k<<<6400, 256, 0, stream>>>(enc_tw,  BtEncT, 394, 128, 128, 512L*3200);
  repack_w_k<<<4800, 256, 0, stream>>>(dec_tw,  BtDP,   327, 128, 128, 384L*3200);
  repack_w_k<<<1600, 256, 0, stream>>>(prior_w, BtDP + 384L*3200, 128, 128, 128, 128L*3200);
  repack_w_k<<<20800,256, 0, stream>>>(enc_gw,  BtEncG, 512, 394, 416, 512L*10400);
  repack_w_k<<<17600,256, 0, stream>>>(dec_gw,  BtDecG, 512, 327, 352, 512L*8800);
  wcomb_k<<<24, 256, 0, stream>>>(write_w, obs_w, Wcomb);
  xr_k<<<192, 256, 0, stream>>>(x, read_w, XR);
  st_enc_k<<<(int)(((long)MTOT*266 + 255)/256), 256, 0, stream>>>(XR, v, r, STenc);
  st_dec_k<<<(int)(((long)MTOT*263 + 255)/256), 256, 0, stream>>>(v, r, STdec);

  for (int t = 0; t < 8; ++t) {
    // merged: z=0 sDec=decT(hDec)+tb+ST & PriorO ; z=1 sEnc=encT(hEnc)+tb+ST+hDec
    conv_tp<<<dim3(64,4,2), 512, 0, stream>>>(
        hDec, BtDP, dec_tb, prior_b, PriorO, sDec, STdec,
        hEnc, BtEncT, enc_tb, sEnc, STenc);
    // enc gates, split-K=2 (partials, bias deferred to lstm2)
    conv_split<416><<<dim3(64,4,2), 512, 0, stream>>>(sEnc, BtEncG, PG0, PG1);
    lstm2_k<<<8192, 256, 0, stream>>>(PG0, PG1, enc_gb, cEnc, hEnc);
    // post = conv(h_enc) -> f32
    conv_gemm<64,64,128,0><<<dim3(256,2), 256, 0, stream>>>(hEnc, BtPost, post_b, PostO);
    // z -> add into sDec ch0..63 ; KL partials
    zkl_k<<<4096, 256, 0, stream>>>(PostO, PriorO, eps + (long)t*64*64*256,
                                    sDec, KLpart + (long)t*4096);
    // dec gates, split-K=2
    conv_split<352><<<dim3(64,4,2), 512, 0, stream>>>(sDec, BtDecG, PG0, PG1);
    lstm2_k<<<8192, 256, 0, stream>>>(PG0, PG1, dec_gb, cDec, hDec);
    // canvas accumulate (write conv fused with obs 1x1)
    wrc_k<<<1024, 256, 0, stream>>>(hDec, Wcomb, Ucomb);
  }

  canvas_k<<<3072, 256, 0, stream>>>(Ucomb, obs_b, out);
  klred_k<<<1, 256, 0, stream>>>(KLpart, out);
}

// Round 8
// 3991.713 us; speedup vs baseline: 1.3277x; 1.0039x over previous
//
#include <hip/hip_runtime.h>
#include <hip/hip_bf16.h>

using bf16 = __hip_bfloat16;
typedef __attribute__((ext_vector_type(8))) short short8;
typedef __attribute__((ext_vector_type(4))) float f32x4;

#define DEVI __device__ __forceinline__

#define MTOT 16384      // 64 * 16 * 16 output positions
#define PADS 25600      // 64 * 20 * 20 padded positions

DEVI float sigm_(float x){ return 1.f/(1.f+expf(-x)); }

// padded spatial index (row) for interior position m = ((nb*16)+iy)*16+ix
DEVI long pidx_(int m){
  int nb = m>>8, iy=(m>>4)&15, ix=m&15;
  return (long)(nb*20 + iy + 2)*20 + (ix + 2);
}

// async global->LDS, 16B per lane. LDS dest = wave-uniform base + lane*16.
DEVI void async16(const void* g, void* l) {
  __builtin_amdgcn_global_load_lds(
      (__attribute__((address_space(1))) void*)(unsigned long long)g,
      (__attribute__((address_space(3))) void*)(unsigned int)(unsigned long long)l,
      16, 0, 0);
}

// fused counted-vmcnt wait + barrier (single asm so no loads slip between)
template<int N> DEVI void waitbar(){
  if constexpr (N==0)      asm volatile("s_waitcnt vmcnt(0)\ns_barrier" ::: "memory");
  else if constexpr (N==3) asm volatile("s_waitcnt vmcnt(3)\ns_barrier" ::: "memory");
  else                     asm volatile("s_waitcnt vmcnt(6)\ns_barrier" ::: "memory");
}

// ---------------------------------------------------------------------------
// DEEP 1-block/CU gates GEMM. BM=256, BN=128, BK=32, 8 waves 4Mx2N (64x64/wave).
// Quad-buffered LDS (96KB), prefetch depth 3, counted vmcnt(6) (never drains
// mid-loop), ALL 8 frag ds_reads issued BEFORE the wait+barrier (read latency
// hides under barrier wait; MFMA-only region after). 1 block/CU, 2 waves/SIMD,
// register budget ~170 unified (fits 256 @ 2 waves/SIMD).
// Explicit bijective m-cluster swizzle: XCD (bid&7) owns m-tiles [r*8,r*8+8)
// x all 4 n-groups -> A-tap re-reads stay L2-resident (1.7MB/XCD), n-copies
// of each m-tile share one L2 (r7's property, r6's failure avoided).
// Output: gates bf16 stride 512, + bias.
// ---------------------------------------------------------------------------
template<int CA>
__global__ __launch_bounds__(512)
void conv_deep(const bf16* __restrict__ A, const bf16* __restrict__ Bt,
               const float* __restrict__ bias, bf16* __restrict__ outB)
{
  constexpr int Kp = 25*CA;
  constexpr int NS = Kp/32;
  __shared__ alignas(16) bf16 As[4][256*32];   // 16KB each
  __shared__ alignas(16) bf16 Bs[4][128*32];   // 8KB each

  const int bid = blockIdx.x;
  const int r8 = bid & 7, q = bid >> 3;
  const int m0 = (((r8<<3) + (q>>2))) << 8;
  const int n0 = (q & 3) << 7;

  const int tid = threadIdx.x;
  const int wv = tid>>6, ln = tid&63;

  // staging: A 256x32 = 1024 chunks of 16B (thread t -> chunks t, t+512);
  // B 128x32 = 512 chunks. row = chunk>>2; phys chunk holds logical
  // chunk ^ ((row>>1)&3) via pre-swizzled global source (0 conflicts r2-r7).
  const int rA = tid>>2;
  const int qs = ((tid&3) ^ ((rA>>1)&3))<<3;
  const int mA0 = m0 + rA, mA1 = m0 + 128 + rA;
  const long paA0 = ((long)(((mA0>>8)*20 + ((mA0>>4)&15))*20 + (mA0&15)))*CA + qs;
  const long paA1 = ((long)(((mA1>>8)*20 + ((mA1>>4)&15))*20 + (mA1&15)))*CA + qs;
  const long pbB  = (long)(n0 + rA)*Kp + qs;

  int kh=0, kw=0, c0=0, ks=0;
  auto stage = [&](int d){
    const long sh = (long)(kh*20 + kw)*CA + c0;
    char* la = (char*)(&As[d][0]) + (wv<<10);
    char* lb = (char*)(&Bs[d][0]) + (wv<<10);
    async16(A + paA0 + sh, la);
    async16(A + paA1 + sh, la + 8192);
    async16(Bt + pbB + ks, lb);
    ks += 32;
    c0 += 32; if (c0==CA){ c0=0; if(++kw==5){kw=0; ++kh;} }
  };

  f32x4 acc[4][4] = {};
  const int wm = wv>>1, wn = wv&1;
  const int rowA = (wm<<6) + (ln&15);
  const int rowB = (wn<<6) + (ln&15);
  const int kqA = (((ln>>4) ^ ((rowA>>1)&3))<<4);
  const int kqB = (((ln>>4) ^ ((rowB>>1)&3))<<4);

  stage(0); stage(1); stage(2);
  waitbar<6>();                       // sub 0 complete for all waves
  for (int t=0; t<NS; ++t) {
    // 1. read all frags of sub t (buffer confirmed at previous barrier);
    //    reads are in flight while we wait at the barrier below.
    const char* as_ = (const char*)(&As[t&3][0]);
    const char* bs_ = (const char*)(&Bs[t&3][0]);
    short8 af[4], bfr[4];
    #pragma unroll
    for (int mf=0; mf<4; mf++)
      af[mf] = *(const short8*)(as_ + ((rowA + (mf<<4))<<6) + kqA);
    #pragma unroll
    for (int nf=0; nf<4; nf++)
      bfr[nf] = *(const short8*)(bs_ + ((rowB + (nf<<4))<<6) + kqB);
    // 2. issue DMA for sub t+3 (writes buffer (t+3)&3 = (t-1)&3, whose readers
    //    finished last phase: reads complete pre-MFMA, barrier closed phase).
    if (t+3 < NS) { stage((t+3)&3); waitbar<6>(); }   // confirm sub t+1
    else if (t+2 < NS) waitbar<3>();
    else waitbar<0>();
    // 3. MFMA-only region
    __builtin_amdgcn_s_setprio(1);
    #pragma unroll
    for (int mf=0; mf<4; mf++)
      #pragma unroll
      for (int nf=0; nf<4; nf++)
        acc[mf][nf] = __builtin_amdgcn_mfma_f32_16x16x32_bf16(af[mf], bfr[nf], acc[mf][nf], 0,0,0);
    __builtin_amdgcn_s_setprio(0);
    asm volatile("s_barrier" ::: "memory");           // close phase
  }

  const int mb = m0 + (wm<<6);
  const int nb = n0 + (wn<<6);
  const int ml = (ln>>4)<<2;
  const int nl = ln&15;
  #pragma unroll
  for (int mf=0; mf<4; mf++) {
    #pragma unroll
    for (int j=0; j<4; j++) {
      const int m = mb + (mf<<4) + ml + j;
      #pragma unroll
      for (int nf=0; nf<4; nf++) {
        const int n = nb + (nf<<4) + nl;
        outB[((long)m<<9) + n] = __float2bfloat16(acc[mf][nf][j] + bias[n]);
      }
    }
  }
}

// ---------------------------------------------------------------------------
// r7-proven 8-wave conv body (BM=256, BN=128, BK=32, triple-buffer, depth-2,
// counted vmcnt(3), setprio). Natural/m-clustered ordering handled by caller.
// EPI: 2 = s_enc: bf16 padded stride 416, +b(n<394) +ST +h_dec(n<128)
//      4 = fused decT+prior: n<352 -> sDec (+b(n<327)+ST); n>=384 -> PriorO f32
//      6 = bf16 PARTIAL out stride 128, no bias            [split-K post]
// ---------------------------------------------------------------------------
template<int CA, int EPI>
DEVI void conv_body(const bf16* __restrict__ A, const bf16* __restrict__ Bt,
                    const float* __restrict__ bias, const float* __restrict__ bias2,
                    float* __restrict__ outF, bf16* __restrict__ outB,
                    const bf16* __restrict__ ST, const bf16* __restrict__ extra,
                    int s0, int s1, int m0, int n0,
                    bf16* AsBase, bf16* BsBase)
{
  constexpr int Kp = 25*CA;
  const int NS = s1 - s0;

  const int tid = threadIdx.x;
  const int wv = tid>>6, ln = tid&63;

  const int rA = tid>>2;
  const int qs = ((tid&3) ^ ((rA>>1)&3))<<3;
  const int mA0 = m0 + rA, mA1 = m0 + 128 + rA;
  const long paA0 = ((long)(((mA0>>8)*20 + ((mA0>>4)&15))*20 + (mA0&15)))*CA + qs;
  const long paA1 = ((long)(((mA1>>8)*20 + ((mA1>>4)&15))*20 + (mA1&15)))*CA + qs;
  const long pbB  = (long)(n0 + rA)*Kp + qs;

  int kk0 = s0*32;
  int c0 = kk0 % CA;
  int tap = kk0 / CA;
  int kh = tap/5, kw = tap%5;
  int ks = kk0;

  auto stage = [&](int d){
    const long sh = (long)(kh*20 + kw)*CA + c0;
    char* la = (char*)AsBase + d*16384 + (wv<<10);
    char* lb = (char*)BsBase + d*8192  + (wv<<10);
    async16(A + paA0 + sh, la);
    async16(A + paA1 + sh, la + 8192);
    async16(Bt + pbB + ks, lb);
    ks += 32;
    c0 += 32; if (c0==CA){ c0=0; if(++kw==5){kw=0; ++kh;} }
  };

  f32x4 acc[4][4] = {};
  const int wm = wv>>1, wn = wv&1;
  const int rowA = (wm<<6) + (ln&15);
  const int rowB = (wn<<6) + (ln&15);
  const int kqA = (((ln>>4) ^ ((rowA>>1)&3))<<4);
  const int kqB = (((ln>>4) ^ ((rowB>>1)&3))<<4);

  stage(0); stage(1);
  int bc = 0, bs = 2;
  for (int t=0; t<NS; ++t) {
    if (t+1 < NS) waitbar<3>();
    else          waitbar<0>();
    if (t+2 < NS) stage(bs);

    const char* as_ = (const char*)AsBase + bc*16384;
    const char* bs_ = (const char*)BsBase + bc*8192;
    short8 af[4], bfr[4];
    #pragma unroll
    for (int mf=0; mf<4; mf++)
      af[mf] = *(const short8*)(as_ + ((rowA + (mf<<4))<<6) + kqA);
    #pragma unroll
    for (int nf=0; nf<4; nf++)
      bfr[nf] = *(const short8*)(bs_ + ((rowB + (nf<<4))<<6) + kqB);
    __builtin_amdgcn_s_setprio(1);
    #pragma unroll
    for (int mf=0; mf<4; mf++)
      #pragma unroll
      for (int nf=0; nf<4; nf++)
        acc[mf][nf] = __builtin_amdgcn_mfma_f32_16x16x32_bf16(af[mf], bfr[nf], acc[mf][nf], 0,0,0);
    __builtin_amdgcn_s_setprio(0);
    bc = (bc==2)?0:bc+1; bs = (bs==2)?0:bs+1;
  }

  const int mb = m0 + (wm<<6);
  const int nb = n0 + (wn<<6);
  const int ml = (ln>>4)<<2;
  const int nl = ln&15;
  #pragma unroll
  for (int mf=0; mf<4; mf++) {
    #pragma unroll
    for (int j=0; j<4; j++) {
      const int m = mb + (mf<<4) + ml + j;
      const long pI = pidx_(m);
      #pragma unroll
      for (int nf=0; nf<4; nf++) {
        const int n = nb + (nf<<4) + nl;
        const float v = acc[mf][nf][j];
        if constexpr (EPI==2) {
          if (n < 416) {
            float b  = (n < 394) ? bias[n] : 0.f;
            float st = __bfloat162float(ST[(long)m*416 + n]);
            float e  = (n < 128) ? __bfloat162float(extra[(pI<<7) + n]) : 0.f;
            outB[pI*416 + n] = __float2bfloat16(v + b + st + e);
          }
        } else if constexpr (EPI==4) {
          if (n < 352) {
            float b  = (n < 327) ? bias[n] : 0.f;
            float st = __bfloat162float(ST[(long)m*352 + n]);
            outB[pI*352 + n] = __float2bfloat16(v + b + st);
          } else if (n >= 384) {
            outF[((long)m<<7) + (n-384)] = v + bias2[n-384];
          }
        } else { // EPI==6: split-K partial, stride 128, no bias
          outB[((long)m<<7) + n] = __float2bfloat16(v);
        }
      }
    }
  }
}

// merged decT+prior (z=0) and encT (z=1): independent convs, 2 blocks/CU.
__global__ __launch_bounds__(512)
void conv_tp(const bf16* __restrict__ hDec, const bf16* __restrict__ BtDP,
             const float* __restrict__ dec_tb, const float* __restrict__ prior_b,
             float* __restrict__ PriorO, bf16* __restrict__ sDec,
             const bf16* __restrict__ STdec,
             const bf16* __restrict__ hEnc, const bf16* __restrict__ BtEncT,
             const float* __restrict__ enc_tb, bf16* __restrict__ sEnc,
             const bf16* __restrict__ STenc)
{
  __shared__ alignas(16) bf16 As[3][256*32];
  __shared__ alignas(16) bf16 Bs[3][128*32];
  const int m0 = blockIdx.x<<8, n0 = blockIdx.y<<7;
  if (blockIdx.z == 0)
    conv_body<128,4>(hDec, BtDP, dec_tb, prior_b, PriorO, sDec, STdec, nullptr,
                     0, 100, m0, n0, &As[0][0], &Bs[0][0]);
  else
    conv_body<128,2>(hEnc, BtEncT, enc_tb, nullptr, nullptr, sEnc, STenc, hDec,
                     0, 100, m0, n0, &As[0][0], &Bs[0][0]);
}

// post GEMM split-K=4: grid (64,1,4); partial planes of 16384x128 bf16.
__global__ __launch_bounds__(512)
void conv_post(const bf16* __restrict__ hEnc, const bf16* __restrict__ BtPost,
               bf16* __restrict__ PP)
{
  __shared__ alignas(16) bf16 As[3][256*32];
  __shared__ alignas(16) bf16 Bs[3][128*32];
  const int z = blockIdx.z;
  conv_body<128,6>(hEnc, BtPost, nullptr, nullptr, nullptr,
                   PP + (long)z*MTOT*128, nullptr, nullptr,
                   z*25, z*25+25, blockIdx.x<<8, 0, &As[0][0], &Bs[0][0]);
}

// OIHW f32 -> Bt[n=o][k=(kh*5+kw)*CA + c] bf16, rows o>=O and cols c>=I zeroed.
__global__ void repack_w_k(const float* __restrict__ w, bf16* __restrict__ Bt,
                           int O, int I, int CA, long total)
{
  long e = (long)blockIdx.x*256 + threadIdx.x;
  if (e >= total) return;
  const int Kp = 25*CA;
  int o = (int)(e / Kp);
  int k = (int)(e % Kp);
  int blk = k / CA, c = k % CA;
  int kh = blk / 5, kwi = blk % 5;
  float v = 0.f;
  if (o < O && c < I) v = w[((long)o*I + c)*25 + kh*5 + kwi];
  Bt[e] = __float2bfloat16(v);
}

// Wcomb[c][pix*3+o] = sum_m write_w[c,m,ki,kj] * obs_w[o,m]   (pix = ki*4+kj)
__global__ void wcomb_k(const float* __restrict__ ww, const float* __restrict__ ow,
                        float* __restrict__ Wc)
{
  int idx = blockIdx.x*256 + threadIdx.x;
  if (idx >= 128*48) return;
  int c = idx / 48, rst = idx % 48;
  int pix = rst / 3, o = rst % 3;
  int ki = pix >> 2, kj = pix & 3;
  float a = 0.f;
  for (int mm=0; mm<128; mm++)
    a += ww[(((long)c*128 + mm)*4 + ki)*4 + kj] * ow[o*128 + mm];
  Wc[idx] = a;
}

// xr = conv(x, read_w, stride 4), xr[m*3+o]
__global__ void xr_k(const float* __restrict__ x, const float* __restrict__ rw,
                     float* __restrict__ xr)
{
  int idx = blockIdx.x*256 + threadIdx.x;
  if (idx >= MTOT*3) return;
  int m = idx / 3, o = idx % 3;
  int nb = m>>8, iy=(m>>4)&15, ix=m&15;
  float a = 0.f;
  for (int c=0;c<3;c++)
    for (int kh=0;kh<4;kh++)
      for (int kw=0;kw<4;kw++)
        a += x[((long)(nb*3+c)*64 + (iy*4+kh))*64 + (ix*4+kw)] * rw[((o*3+c)*4+kh)*4+kw];
  xr[idx] = a;
}

// static concat part for enc: channels 128..393 of ST_enc (stride 416)
__global__ void st_enc_k(const float* __restrict__ xr, const float* __restrict__ v,
                         const float* __restrict__ r, bf16* __restrict__ ST)
{
  long g = (long)blockIdx.x*256 + threadIdx.x;
  if (g >= (long)MTOT*266) return;
  int m = (int)(g / 266), ch = (int)(g % 266);
  int nb = m>>8, sp = m&255;
  float val;
  if (ch < 3)       val = xr[m*3 + ch];
  else if (ch < 10) val = v[nb*7 + ch - 3];
  else              val = r[((long)nb*256 + (ch-10))*256 + sp];
  ST[(long)m*416 + 128 + ch] = __float2bfloat16(val);
}

// static concat part for dec: channels 64..326 of ST_dec (stride 352)
__global__ void st_dec_k(const float* __restrict__ v, const float* __restrict__ r,
                         bf16* __restrict__ ST)
{
  long g = (long)blockIdx.x*256 + threadIdx.x;
  if (g >= (long)MTOT*263) return;
  int m = (int)(g / 263), ch = (int)(g % 263);
  int nb = m>>8, sp = m&255;
  float val;
  if (ch < 7) val = v[nb*7 + ch];
  else        val = r[((long)nb*256 + (ch-7))*256 + sp];
  ST[(long)m*352 + 64 + ch] = __float2bfloat16(val);
}

// LSTM pointwise: gates (f,i,o,s order, stride 512, bias included) -> c, h
__global__ void lstm_k(const bf16* __restrict__ gates, float* __restrict__ cbuf,
                       bf16* __restrict__ hpad)
{
  int idx = blockIdx.x*256 + threadIdx.x;   // exactly MTOT*128
  int m = idx >> 7, c = idx & 127;
  long gb = (long)m << 9;
  float f = __bfloat162float(gates[gb + c]);
  float i = __bfloat162float(gates[gb + 128 + c]);
  float o = __bfloat162float(gates[gb + 256 + c]);
  float s = __bfloat162float(gates[gb + 384 + c]);
  float cell = sigm_(f)*cbuf[idx] + sigm_(i)*tanhf(s);
  cbuf[idx] = cell;
  hpad[(pidx_(m)<<7) + c] = __float2bfloat16(sigm_(o)*tanhf(cell));
}

// z = q_mu + exp(0.5 q_lv)*eps with q = sum of 4 post partials + bias;
// ADD z into sDec ch 0..63 ; KL partial per block (no contended atomics)
__global__ void zkl4_k(const bf16* __restrict__ PP, const float* __restrict__ pb,
                       const float* __restrict__ prior, const float* __restrict__ eps_t,
                       bf16* __restrict__ sDec, float* __restrict__ part)
{
  __shared__ float wsum[4];
  const long PL = (long)MTOT*128;
  int idx = blockIdx.x*256 + threadIdx.x;   // exactly MTOT*64
  int m = idx >> 6, c = idx & 63;
  float qm = pb[c], ql = pb[64 + c];
  #pragma unroll
  for (int z=0; z<4; ++z) {
    qm += __bfloat162float(PP[z*PL + ((long)m<<7) + c]);
    ql += __bfloat162float(PP[z*PL + ((long)m<<7) + 64 + c]);
  }
  long pbx = (long)m << 7;
  float pm = prior[pbx + c], pl = prior[pbx + 64 + c];
  int nb = m>>8, sp = m&255;
  float e = eps_t[((long)nb*64 + c)*256 + sp];
  float z = qm + expf(0.5f*ql)*e;
  long so = pidx_(m)*352 + c;
  sDec[so] = __float2bfloat16(__bfloat162float(sDec[so]) + z);
  float kl = expf(ql - pl) + (pm-qm)*(pm-qm)*expf(-pl) - 1.f + (pl - ql);
  #pragma unroll
  for (int off=32; off>0; off>>=1) kl += __shfl_down(kl, off);
  if ((threadIdx.x & 63) == 0) wsum[threadIdx.x >> 6] = kl;
  __syncthreads();
  if (threadIdx.x == 0)
    part[blockIdx.x] = wsum[0] + wsum[1] + wsum[2] + wsum[3];
}

// canvas pre-activation accumulate: uc[n,y,x,o] += sum_c h_dec*Wcomb
__global__ __launch_bounds__(256)
void wrc_k(const bf16* __restrict__ hpad, const float* __restrict__ Wc,
           float* __restrict__ uc)
{
  __shared__ float Wl[128*48];
  for (int i = threadIdx.x; i < 128*48; i += 256) Wl[i] = Wc[i];
  __syncthreads();
  int t = threadIdx.x;
  int mloc = t >> 4, pix = t & 15;
  int m = (blockIdx.x<<4) + mloc;
  int nb = m>>8, iy=(m>>4)&15, ix=m&15;
  const bf16* h = hpad + (pidx_(m)<<7);
  float a0=0.f, a1=0.f, a2=0.f;
  for (int c=0;c<128;c++) {
    float hv = __bfloat162float(h[c]);
    const float* wl = Wl + c*48 + pix*3;
    a0 += hv*wl[0]; a1 += hv*wl[1]; a2 += hv*wl[2];
  }
  int ki = pix>>2, kj = pix&3;
  long ob = ((long)((nb<<6) + (iy<<2) + ki)*64 + (ix<<2) + kj)*3;
  uc[ob+0] += a0; uc[ob+1] += a1; uc[ob+2] += a2;
}

__global__ void canvas_k(const float* __restrict__ uc, const float* __restrict__ ob,
                         float* __restrict__ out)
{
  int idx = blockIdx.x*256 + threadIdx.x;   // exactly 786432, NCHW order
  int x = idx & 63, y = (idx>>6)&63;
  int rem = idx >> 12;
  int o = rem % 3, n = rem / 3;
  float v = uc[((long)((n<<6)+y)*64 + x)*3 + o] + ob[o];
  out[idx] = 1.f/(1.f+expf(-v));
}

// final KL: sum 8*4096 per-block partials, scale, write out[786432]
__global__ void klred_k(const float* __restrict__ part, float* __restrict__ out)
{
  __shared__ float wsum[4];
  float a = 0.f;
  for (int i = threadIdx.x; i < 32768; i += 256) a += part[i];
  #pragma unroll
  for (int off=32; off>0; off>>=1) a += __shfl_down(a, off);
  if ((threadIdx.x & 63) == 0) wsum[threadIdx.x >> 6] = a;
  __syncthreads();
  if (threadIdx.x == 0)
    out[786432] = (wsum[0] + wsum[1] + wsum[2] + wsum[3]) * (0.5f/64.f);
}

// ---------------------------------------------------------------------------
// workspace layout (bytes) — unchanged from r7 (proven to fit ws_size)
static const long O_BT_POST  = 0;                     // 128*3200*2
static const long O_BT_ENCT  = O_BT_POST  + 819200;   // 512*3200*2
static const long O_BT_DP    = O_BT_ENCT  + 3276800;  // 512*3200*2
static const long O_BT_ENCG  = O_BT_DP    + 3276800;  // 512*10400*2
static const long O_BT_DECG  = O_BT_ENCG  + 10649600; // 512*8800*2
static const long O_WCOMB    = O_BT_DECG  + 9011200;  // 6144*4
static const long O_XR       = O_WCOMB    + 24576;    // 49152*4
static const long O_KLP      = O_XR       + 196608;   // 32768*4
static const long O_STENC    = O_KLP      + 131072;   // 16384*416*2
static const long O_STDEC    = O_STENC    + 13631488; // 16384*352*2
static const long O_HENC     = O_STDEC    + 11534336; // 25600*128*2
static const long O_HDEC     = O_HENC     + 6553600;
static const long O_SENC     = O_HDEC     + 6553600;  // 25600*416*2
static const long O_SDEC     = O_SENC     + 21299200; // 25600*352*2
static const long O_CENC     = O_SDEC     + 18022400; // 16384*128*4
static const long O_CDEC     = O_CENC     + 8388608;
static const long O_PRIOR    = O_CDEC     + 8388608;  // 16384*128*4
static const long O_POST     = O_PRIOR    + 8388608;  // (unused this round)
static const long O_PG0      = O_POST     + 8388608;  // Gates: 16384*512*2
static const long O_PG1      = O_PG0      + 16777216; // post partials: 4 planes
static const long O_UC       = O_PG1      + 16777216; // 786432*4
static const long WS_TOTAL   = O_UC       + 3145728;

extern "C" void kernel_launch(void* const* d_in, const int* in_sizes, int n_in,
                              void* d_out, int out_size, void* d_ws, size_t ws_size,
                              hipStream_t stream)
{
  const float* x       = (const float*)d_in[0];
  const float* v       = (const float*)d_in[1];
  const float* r       = (const float*)d_in[2];
  const float* eps     = (const float*)d_in[3];
  const float* read_w  = (const float*)d_in[4];
  const float* write_w = (const float*)d_in[5];
  const float* prior_w = (const float*)d_in[6];
  const float* prior_b = (const float*)d_in[7];
  const float* post_w  = (const float*)d_in[8];
  const float* post_b  = (const float*)d_in[9];
  const float* enc_gw  = (const float*)d_in[10];
  const float* enc_gb  = (const float*)d_in[11];
  const float* enc_tw  = (const float*)d_in[12];
  const float* enc_tb  = (const float*)d_in[13];
  const float* dec_gw  = (const float*)d_in[14];
  const float* dec_gb  = (const float*)d_in[15];
  const float* dec_tw  = (const float*)d_in[16];
  const float* dec_tb  = (const float*)d_in[17];
  const float* obs_w   = (const float*)d_in[18];
  const float* obs_b   = (const float*)d_in[19];

  char* ws = (char*)d_ws;
  bf16* BtPost  = (bf16*)(ws + O_BT_POST);
  bf16* BtEncT  = (bf16*)(ws + O_BT_ENCT);
  bf16* BtDP    = (bf16*)(ws + O_BT_DP);
  bf16* BtEncG  = (bf16*)(ws + O_BT_ENCG);
  bf16* BtDecG  = (bf16*)(ws + O_BT_DECG);
  float* Wcomb  = (float*)(ws + O_WCOMB);
  float* XR     = (float*)(ws + O_XR);
  float* KLpart = (float*)(ws + O_KLP);
  bf16* STenc   = (bf16*)(ws + O_STENC);
  bf16* STdec   = (bf16*)(ws + O_STDEC);
  bf16* hEnc    = (bf16*)(ws + O_HENC);
  bf16* hDec    = (bf16*)(ws + O_HDEC);
  bf16* sEnc    = (bf16*)(ws + O_SENC);
  bf16* sDec    = (bf16*)(ws + O_SDEC);
  float* cEnc   = (float*)(ws + O_CENC);
  float* cDec   = (float*)(ws + O_CDEC);
  float* PriorO = (float*)(ws + O_PRIOR);
  bf16* Gates   = (bf16*)(ws + O_PG0);
  bf16* PostP   = (bf16*)(ws + O_PG1);
  float* Ucomb  = (float*)(ws + O_UC);
  float* out    = (float*)d_out;

  size_t clr = (size_t)WS_TOTAL; if (clr > ws_size) clr = ws_size;
  hipMemsetAsync(d_ws, 0, clr, stream);

  // weight repacks
  repack_w_k<<<1600, 256, 0, stream>>>(post_w,  BtPost, 128, 128, 128, 128L*3200);
  repack_w_k<<<6400, 256, 0, stream>>>(enc_tw,  BtEncT, 394, 128, 128, 512L*3200);
  repack_w_k<<<4800, 256, 0, stream>>>(dec_tw,  BtDP,   327, 128, 128, 384L*3200);
  repack_w_k<<<1600, 256, 0, stream>>>(prior_w, BtDP + 384L*3200, 128, 128, 128, 128L*3200);
  repack_w_k<<<20800,256, 0, stream>>>(enc_gw,  BtEncG, 512, 394, 416, 512L*10400);
  repack_w_k<<<17600,256, 0, stream>>>(dec_gw,  BtDecG, 512, 327, 352, 512L*8800);
  wcomb_k<<<24, 256, 0, stream>>>(write_w, obs_w, Wcomb);
  xr_k<<<192, 256, 0, stream>>>(x, read_w, XR);
  st_enc_k<<<(int)(((long)MTOT*266 + 255)/256), 256, 0, stream>>>(XR, v, r, STenc);
  st_dec_k<<<(int)(((long)MTOT*263 + 255)/256), 256, 0, stream>>>(v, r, STdec);

  for (int t = 0; t < 8; ++t) {
    // merged: z=0 sDec=decT(hDec)+tb+ST & PriorO ; z=1 sEnc=encT(hEnc)+tb+ST+hDec
    conv_tp<<<dim3(64,4,2), 512, 0, stream>>>(
        hDec, BtDP, dec_tb, prior_b, PriorO, sDec, STdec,
        hEnc, BtEncT, enc_tb, sEnc, STenc);
    // enc gates: deep 1-block/CU pipeline
    conv_deep<416><<<256, 512, 0, stream>>>(sEnc, BtEncG, enc_gb, Gates);
    lstm_k<<<8192, 256, 0, stream>>>(Gates, cEnc, hEnc);
    // post split-K=4 -> partial planes
    conv_post<<<dim3(64,1,4), 512, 0, stream>>>(hEnc, BtPost, PostP);
    // z (sum partials + bias) -> add into sDec ch0..63 ; KL partials
    zkl4_k<<<4096, 256, 0, stream>>>(PostP, post_b, PriorO,
                                     eps + (long)t*64*64*256, sDec,
                                     KLpart + (long)t*4096);
    // dec gates: deep pipeline
    conv_deep<352><<<256, 512, 0, stream>>>(sDec, BtDecG, dec_gb, Gates);
    lstm_k<<<8192, 256, 0, stream>>>(Gates, cDec, hDec);
    // canvas accumulate (write conv fused with obs 1x1)
    wrc_k<<<1024, 256, 0, stream>>>(hDec, Wcomb, Ucomb);
  }

  canvas_k<<<3072, 256, 0, stream>>>(Ucomb, obs_b, out);
  klred_k<<<1, 256, 0, stream>>>(KLpart, out);
}